// Round 1
// baseline (5630.061 us; speedup 1.0000x reference)
//
#include <hip/hip_runtime.h>
#include <hip/hip_bf16.h>

#define B_ 64
#define T_ 512
#define I_ 512
#define O_ 512
#define K_ 1024
#define N_ 2048
#define EPSF 1e-5f

typedef __attribute__((ext_vector_type(8))) short short8v;
typedef __attribute__((ext_vector_type(4))) float f32x4;
typedef unsigned short u16;

__device__ __forceinline__ u16 f2bf(float f) {
    union { float f; unsigned u; } v; v.f = f;
    unsigned r = v.u + 0x7fffu + ((v.u >> 16) & 1u);   // round-to-nearest-even
    return (u16)(r >> 16);
}

// ---------------- init: transpose + convert W -> wt[n][k] bf16 ----------------
__global__ void k_init_wt(const float* __restrict__ W, u16* __restrict__ wt) {
    int n = blockIdx.x;                       // 0..2047
    for (int k = threadIdx.x; k < K_; k += 256)
        wt[(size_t)n * K_ + k] = f2bf(W[(size_t)k * N_ + n]);
}

// ---------------- init: state h (bf16) and c (fp32) ----------------
__global__ void k_init_state(const float* __restrict__ hx, const float* __restrict__ cx,
                             u16* __restrict__ hbf, float* __restrict__ cst) {
    int gid = blockIdx.x * 256 + threadIdx.x; // 0..32767
    int o = gid & (O_ - 1);
    hbf[gid] = f2bf(hx[o]);
    cst[gid] = cx[o];
}

// ---------------- per-step GEMM: comb = [x_t | h] @ W + b ----------------
// grid 128 wgs x 256 thr; wg -> 16 cols (n0 = blk*16); wave w -> rows 16w..16w+15
__global__ void k_gemm(const float* __restrict__ x, const u16* __restrict__ wt,
                       const u16* __restrict__ hbf, const float* __restrict__ bias,
                       float* __restrict__ comb, int t) {
    __shared__ char smem[65536];              // 64 rows x 512 k bf16 (one K-chunk)
    const int tid = threadIdx.x;
    const int n0 = blockIdx.x * 16;
    const int w = tid >> 6, l = tid & 63;
    const int rl = l & 15, kg = l >> 4;       // row-in-tile, k-group
    const int row = 16 * w + rl;

    f32x4 acc = {0.f, 0.f, 0.f, 0.f};

    for (int c = 0; c < 2; ++c) {
        // ---- stage A chunk (64 rows x 512 k) into LDS as bf16, XOR-swizzled ----
        if (c == 0) {
            // x_t part: fp32 -> bf16
            for (int it = 0; it < 16; ++it) {
                int idx = tid + 256 * it;     // 0..4095 (64 rows * 64 16B-chunks)
                int r = idx >> 6, ck = idx & 63, k0 = ck * 8;
                const float* src = x + (size_t)r * T_ * I_ + (size_t)t * I_ + k0;
                float4 p = *(const float4*)src;
                float4 q = *(const float4*)(src + 4);
                short8v v;
                v[0] = (short)f2bf(p.x); v[1] = (short)f2bf(p.y);
                v[2] = (short)f2bf(p.z); v[3] = (short)f2bf(p.w);
                v[4] = (short)f2bf(q.x); v[5] = (short)f2bf(q.y);
                v[6] = (short)f2bf(q.z); v[7] = (short)f2bf(q.w);
                int byte = r * 1024 + ((k0 * 2) ^ ((r & 7) << 4));
                *(short8v*)(smem + byte) = v;
            }
        } else {
            // h part: already bf16
            for (int it = 0; it < 16; ++it) {
                int idx = tid + 256 * it;
                int r = idx >> 6, ck = idx & 63, k0 = ck * 8;
                short8v v = *(const short8v*)(hbf + r * O_ + k0);
                int byte = r * 1024 + ((k0 * 2) ^ ((r & 7) << 4));
                *(short8v*)(smem + byte) = v;
            }
        }
        __syncthreads();

        // ---- compute: 16 MFMAs per wave over this K-chunk ----
        const int kbase = c * 512;
        const u16* wcol = wt + (size_t)(n0 + rl) * K_ + kbase;
#pragma unroll
        for (int kc = 0; kc < 16; ++kc) {
            int kloc = kc * 32 + kg * 8;
            short8v a = *(const short8v*)(smem + row * 1024 + ((kloc * 2) ^ ((rl & 7) << 4)));
            short8v bb = *(const short8v*)(wcol + kloc);
            acc = __builtin_amdgcn_mfma_f32_16x16x32_bf16(a, bb, acc, 0, 0, 0);
        }
        __syncthreads();
    }

    // ---- epilogue: C/D mapping col=l&15, row=(l>>4)*4+j (m89-verified) ----
    int col = n0 + rl;
    float bv = bias[col];
    int row0 = 16 * w + kg * 4;
#pragma unroll
    for (int j = 0; j < 4; ++j)
        comb[(size_t)(row0 + j) * N_ + col] = acc[j] + bv;
}

// ---------------- per-step LN + gates + state update ----------------
// grid 64 wgs (one per batch row) x 256 thr
__global__ void k_update(const float* __restrict__ comb, const float* __restrict__ lnw,
                         const float* __restrict__ lnb, float* __restrict__ cst,
                         u16* __restrict__ hbf, float* __restrict__ out, int t) {
    __shared__ float sc[2048];
    __shared__ float sred[8];
    int b = blockIdx.x, tid = threadIdx.x;
    const float* cr = comb + (size_t)b * N_;

    float4 v0 = *(const float4*)(cr + tid * 8);
    float4 v1 = *(const float4*)(cr + tid * 8 + 4);
    *(float4*)(sc + tid * 8) = v0;
    *(float4*)(sc + tid * 8 + 4) = v1;

    float s = v0.x + v0.y + v0.z + v0.w + v1.x + v1.y + v1.z + v1.w;
    float q = v0.x*v0.x + v0.y*v0.y + v0.z*v0.z + v0.w*v0.w
            + v1.x*v1.x + v1.y*v1.y + v1.z*v1.z + v1.w*v1.w;
#pragma unroll
    for (int off = 32; off > 0; off >>= 1) {
        s += __shfl_down(s, off);
        q += __shfl_down(q, off);
    }
    if ((tid & 63) == 0) { sred[(tid >> 6) * 2] = s; sred[(tid >> 6) * 2 + 1] = q; }
    __syncthreads();
    s = sred[0] + sred[2] + sred[4] + sred[6];
    q = sred[1] + sred[3] + sred[5] + sred[7];

    float mu = s * (1.0f / 2048.0f);
    float var = q * (1.0f / 2048.0f) - mu * mu;
    float rstd = rsqrtf(var + EPSF);

#pragma unroll
    for (int j = 0; j < 2; ++j) {
        int o = tid + j * 256;
        float n0 = (sc[o]        - mu) * rstd * lnw[o]        + lnb[o];
        float n1 = (sc[o + 512]  - mu) * rstd * lnw[o + 512]  + lnb[o + 512];
        float n2 = (sc[o + 1024] - mu) * rstd * lnw[o + 1024] + lnb[o + 1024];
        float n3 = (sc[o + 1536] - mu) * rstd * lnw[o + 1536] + lnb[o + 1536];
        float ig = 1.f / (1.f + __expf(-n0));
        float fg = 1.f / (1.f + __expf(-n1));
        float og = 1.f / (1.f + __expf(-n2));
        float e2 = __expf(-2.f * fabsf(n3));
        float th = copysignf((1.f - e2) / (1.f + e2), n3);
        float cc = fg * cst[b * O_ + o] + ig * th;
        float h = og * cc;
        cst[b * O_ + o] = cc;
        hbf[b * O_ + o] = f2bf(h);
        out[(size_t)b * T_ * O_ + (size_t)t * O_ + o] = h;
    }
}

extern "C" void kernel_launch(void* const* d_in, const int* in_sizes, int n_in,
                              void* d_out, int out_size, void* d_ws, size_t ws_size,
                              hipStream_t stream) {
    const float* x    = (const float*)d_in[0];
    const float* W    = (const float*)d_in[1];
    const float* bias = (const float*)d_in[2];
    const float* lnw  = (const float*)d_in[3];
    const float* lnb  = (const float*)d_in[4];
    const float* hx   = (const float*)d_in[5];
    const float* cx   = (const float*)d_in[6];
    float* out = (float*)d_out;

    char* ws = (char*)d_ws;
    u16*   wt   = (u16*)ws;                                     // 4 MiB
    u16*   hbf  = (u16*)(ws + 4u * 1024 * 1024);                // 64 KiB
    float* cst  = (float*)(ws + 4u * 1024 * 1024 + 65536u);     // 128 KiB
    float* comb = (float*)(ws + 4u * 1024 * 1024 + 65536u + 131072u); // 512 KiB

    k_init_wt<<<2048, 256, 0, stream>>>(W, wt);
    k_init_state<<<128, 256, 0, stream>>>(hx, cx, hbf, cst);

    for (int t = 0; t < T_; ++t) {
        k_gemm<<<128, 256, 0, stream>>>(x, wt, hbf, bias, comb, t);
        k_update<<<64, 256, 0, stream>>>(comb, lnw, lnb, cst, hbf, out, t);
    }
}